// Round 1
// baseline (281.082 us; speedup 1.0000x reference)
//
#include <hip/hip_runtime.h>
#include <hip/hip_fp16.h>

#define H_  64      // B*N heads
#define D_  128
#define L_  2048
#define LT_ 16      // L_/128 tiles
#define RSCALE 0.08838834764831845f   // 1/sqrt(128)

typedef _Float16 half8 __attribute__((ext_vector_type(8)));
typedef float    f32x4 __attribute__((ext_vector_type(4)));

__device__ __forceinline__ void gload16(const void* g, void* l) {
    __builtin_amdgcn_global_load_lds(
        (const __attribute__((address_space(1))) void*)g,
        (__attribute__((address_space(3))) void*)l,
        16, 0, 0);
}

// ---------------------------------------------------------------------------
// Kernel 1: x [H][D][L] fp32  ->  xt [H][L][D] fp16  (transpose + convert)
// ---------------------------------------------------------------------------
__global__ __launch_bounds__(256) void k_transpose(const float* __restrict__ x,
                                                   __half* __restrict__ xt) {
    const int h  = blockIdx.x;
    const int lc = blockIdx.y;             // chunk of 64 l-values
    __shared__ float raw[128][65];
    const float* xh = x + (size_t)h * D_ * L_ + (size_t)lc * 64;
    const int t = threadIdx.x;
    const int r0 = t >> 4;                 // 0..15
    const int c4 = (t & 15) << 2;          // 0,4,..,60
#pragma unroll
    for (int i = 0; i < 8; ++i) {
        const int d = i * 16 + r0;
        const float4 v = *(const float4*)(xh + (size_t)d * L_ + c4);
        raw[d][c4 + 0] = v.x; raw[d][c4 + 1] = v.y;
        raw[d][c4 + 2] = v.z; raw[d][c4 + 3] = v.w;
    }
    __syncthreads();
    const int lane = t & 63, w = t >> 6;
    __half2* xth = (__half2*)(xt + (size_t)h * L_ * D_ + (size_t)lc * 64 * D_);
#pragma unroll
    for (int i = 0; i < 16; ++i) {
        const int jl = w * 16 + i;
        const float a = raw[2 * lane][jl];
        const float b = raw[2 * lane + 1][jl];
        xth[(size_t)jl * 64 + lane] = __floats2half2_rn(a, b);
    }
}

// ---------------------------------------------------------------------------
// Kernel 2 (template): fused Gram-GEMM tile + exp epilogue.
// PASS 1: row sums of exp(S/scale)  -> zw = Zpart[h][ct][l]   (unique slots)
// PASS 2: col sums of a[l]*exp(...) -> zw = Wpart[h][rt][m]   (unique slots)
// Tile 128x128, K=128 (full), 4 waves (2x2), MFMA 16x16x32 f16.
// ---------------------------------------------------------------------------
template <int PASS>
__global__ __launch_bounds__(256, 2) void k_gemm(const __half* __restrict__ xt,
                                                 const float* __restrict__ ainv,
                                                 float* __restrict__ zw) {
    __shared__ char  sm[65536];            // Ta 32K | Tb 32K (swizzled rows)
    __shared__ float red[2][128];
    __shared__ float asv[128];

    const int h  = blockIdx.y;
    const int rt = blockIdx.x >> 4;
    const int ct = blockIdx.x & 15;

    const int t    = threadIdx.x;
    const int lane = t & 63;
    const int wid  = t >> 6;
    const int wr   = wid >> 1, wc = wid & 1;

    const char* xh = (const char*)(xt + (size_t)h * L_ * D_);  // rows of 256B

    // ---- stage both tiles via global_load_lds (linear LDS dest, pre-swizzled src)
#pragma unroll
    for (int tile = 0; tile < 2; ++tile) {
        const int col0 = (tile ? ct : rt) * 128;
        const char* src = xh + (size_t)col0 * 256;
        char* dst = sm + tile * 32768;
#pragma unroll
        for (int i = 0; i < 8; ++i) {
            const unsigned o   = (unsigned)(wid * 8 + i) * 1024u + (unsigned)lane * 16u;
            const unsigned row = o >> 8;
            const unsigned so  = (o & ~255u) | ((o & 255u) ^ ((row & 7u) << 4));
            gload16(src + so, dst + (size_t)(wid * 8 + i) * 1024);
        }
    }
    if (PASS == 2 && t < 128) asv[t] = ainv[((size_t)h << 11) + rt * 128 + t];
    __syncthreads();

    // ---- MFMA compute: each wave owns a 64x64 sub-tile
    const char* ta = sm;
    const char* tb = sm + 32768;
    const int lo = lane & 15, hi = lane >> 4;
    const unsigned sx = (unsigned)((lane & 7) << 4);   // read-side swizzle term
    f32x4 acc[4][4] = {};
#pragma unroll
    for (int s = 0; s < 4; ++s) {
        half8 a[4], b[4];
        const unsigned inr = ((unsigned)(s * 64 + hi * 16)) ^ sx;
#pragma unroll
        for (int f = 0; f < 4; ++f) {
            const unsigned rowA = (unsigned)(wr * 64 + f * 16 + lo);
            a[f] = *(const half8*)(ta + rowA * 256 + inr);
            const unsigned rowB = (unsigned)(wc * 64 + f * 16 + lo);
            b[f] = *(const half8*)(tb + rowB * 256 + inr);
        }
#pragma unroll
        for (int fm = 0; fm < 4; ++fm)
#pragma unroll
            for (int fn = 0; fn < 4; ++fn)
                acc[fm][fn] = __builtin_amdgcn_mfma_f32_16x16x32_f16(
                    a[fm], b[fn], acc[fm][fn], 0, 0, 0);
    }

    // ---- epilogue
    if (PASS == 1) {
        float rs[4][4];
#pragma unroll
        for (int fm = 0; fm < 4; ++fm)
#pragma unroll
            for (int r = 0; r < 4; ++r) rs[fm][r] = 0.0f;
#pragma unroll
        for (int fm = 0; fm < 4; ++fm)
#pragma unroll
            for (int fn = 0; fn < 4; ++fn)
#pragma unroll
                for (int r = 0; r < 4; ++r)
                    rs[fm][r] += __expf(acc[fm][fn][r] * RSCALE);
#pragma unroll
        for (int dm = 1; dm < 16; dm <<= 1)
#pragma unroll
            for (int fm = 0; fm < 4; ++fm)
#pragma unroll
                for (int r = 0; r < 4; ++r)
                    rs[fm][r] += __shfl_xor(rs[fm][r], dm, 64);
        if (lo == 0) {
#pragma unroll
            for (int fm = 0; fm < 4; ++fm)
#pragma unroll
                for (int r = 0; r < 4; ++r)
                    red[wc][wr * 64 + fm * 16 + hi * 4 + r] = rs[fm][r];
        }
        __syncthreads();
        if (t < 128)
            zw[(((size_t)h * LT_ + ct) << 11) + rt * 128 + t] = red[0][t] + red[1][t];
    } else {
        float cs[4] = {0.0f, 0.0f, 0.0f, 0.0f};
#pragma unroll
        for (int fm = 0; fm < 4; ++fm) {
            float av[4];
#pragma unroll
            for (int r = 0; r < 4; ++r)
                av[r] = asv[wr * 64 + fm * 16 + hi * 4 + r];
#pragma unroll
            for (int fn = 0; fn < 4; ++fn)
#pragma unroll
                for (int r = 0; r < 4; ++r)
                    cs[fn] += __expf(acc[fm][fn][r] * RSCALE) * av[r];
        }
#pragma unroll
        for (int dm = 16; dm < 64; dm <<= 1)
#pragma unroll
            for (int fn = 0; fn < 4; ++fn)
                cs[fn] += __shfl_xor(cs[fn], dm, 64);
        if (hi == 0) {
#pragma unroll
            for (int fn = 0; fn < 4; ++fn)
                red[wr][wc * 64 + fn * 16 + lo] = cs[fn];
        }
        __syncthreads();
        if (t < 128)
            zw[(((size_t)h * LT_ + rt) << 11) + ct * 128 + t] = red[0][t] + red[1][t];
    }
}

// ---------------------------------------------------------------------------
// Kernel 3: Z[h][l] = sum_ct Zpart ; Ainv = 1/Z
// ---------------------------------------------------------------------------
__global__ __launch_bounds__(256) void k_reduceZ(const float* __restrict__ zp,
                                                 float* __restrict__ ainv) {
    const int i = blockIdx.x * 256 + threadIdx.x;   // over H_*L_
    const int h = i >> 11, l = i & 2047;
    float z = 0.0f;
#pragma unroll
    for (int ct = 0; ct < LT_; ++ct)
        z += zp[(((size_t)h * LT_ + ct) << 11) + l];
    ainv[i] = 1.0f / z;
}

// ---------------------------------------------------------------------------
// Kernel 4: w[m] = sum_rt Wpart ; out[h][d] = (1/L) * sum_m x[h][d][m]*w[m]
// grid: H_*4 blocks, each handles 32 d-rows (one wave per row-iteration)
// ---------------------------------------------------------------------------
__global__ __launch_bounds__(256) void k_out(const float* __restrict__ x,
                                             const float* __restrict__ wpart,
                                             float* __restrict__ out) {
    __shared__ float wl[L_];
    const int h = blockIdx.x >> 2, q = blockIdx.x & 3;
    const int t = threadIdx.x, lane = t & 63, wid = t >> 6;
    for (int c = t; c < L_; c += 256) {
        float s = 0.0f;
#pragma unroll
        for (int rt = 0; rt < LT_; ++rt)
            s += wpart[(((size_t)h * LT_ + rt) << 11) + c];
        wl[c] = s;
    }
    __syncthreads();
#pragma unroll 1
    for (int it = 0; it < 8; ++it) {
        const int d = q * 32 + wid * 8 + it;
        const float* xr = x + ((size_t)h * D_ + d) * L_;
        float s = 0.0f;
#pragma unroll
        for (int kk = 0; kk < 8; ++kk) {
            const int m = kk * 256 + lane * 4;
            const float4 xv = *(const float4*)(xr + m);
            const float4 wv = *(const float4*)(wl + m);
            s += xv.x * wv.x + xv.y * wv.y + xv.z * wv.z + xv.w * wv.w;
        }
#pragma unroll
        for (int dm = 1; dm < 64; dm <<= 1) s += __shfl_xor(s, dm, 64);
        if (lane == 0) out[(size_t)h * D_ + d] = s * (1.0f / (float)L_);
    }
}

// ---------------------------------------------------------------------------
extern "C" void kernel_launch(void* const* d_in, const int* in_sizes, int n_in,
                              void* d_out, int out_size, void* d_ws, size_t ws_size,
                              hipStream_t stream) {
    const float* x = (const float*)d_in[0];
    float* out = (float*)d_out;
    char* ws = (char*)d_ws;

    // workspace layout (bytes)
    __half* xt  = (__half*)(ws);                               // 33,554,432
    float* zp   = (float*)(ws + 33554432);                     //  8,388,608
    float* ainv = (float*)(ws + 33554432 + 8388608);           //    524,288
    float* wp   = (float*)(ws + 33554432 + 8388608 + 524288);  //  8,388,608

    k_transpose<<<dim3(H_, L_ / 64), 256, 0, stream>>>(x, xt);
    k_gemm<1><<<dim3(LT_ * LT_, H_), 256, 0, stream>>>(xt, ainv, zp);
    k_reduceZ<<<(H_ * L_) / 256, 256, 0, stream>>>(zp, ainv);
    k_gemm<2><<<dim3(LT_ * LT_, H_), 256, 0, stream>>>(xt, ainv, wp);
    k_out<<<H_ * 4, 256, 0, stream>>>(x, wp, out);
}

// Round 2
// 170.157 us; speedup vs baseline: 1.6519x; 1.6519x over previous
//
#include <hip/hip_runtime.h>
#include <hip/hip_fp16.h>

#define H_  64      // B*N heads
#define D_  128
#define L_  2048
#define RSCALE 0.08838834764831845f   // 1/sqrt(128)

typedef _Float16 half8 __attribute__((ext_vector_type(8)));
typedef float    f32x4 __attribute__((ext_vector_type(4)));

__device__ __forceinline__ void gload16(const void* g, void* l) {
    __builtin_amdgcn_global_load_lds(
        (const __attribute__((address_space(1))) void*)g,
        (__attribute__((address_space(3))) void*)l,
        16, 0, 0);
}

// Stage NSW KB-sweeps per wave: linear LDS dest, pre-swizzled global source.
// Swizzle: within each 256B row, byte ^= (row&7)<<4  (matches read side).
template <int NSW>
__device__ __forceinline__ void stage_tile(const char* __restrict__ src,
                                           char* __restrict__ dst,
                                           int wid, int lane) {
#pragma unroll
    for (int j = 0; j < NSW; ++j) {
        const unsigned o   = (unsigned)(wid * NSW + j) * 1024u + (unsigned)lane * 16u;
        const unsigned row = o >> 8;
        const unsigned so  = (o & ~255u) | ((o & 255u) ^ ((row & 7u) << 4));
        gload16(src + so, dst + (size_t)(wid * NSW + j) * 1024u);
    }
}

// ---------------------------------------------------------------------------
// Kernel 1: x [H][D][L] fp32  ->  xt [H][L][D] fp16  (transpose + convert)
// ---------------------------------------------------------------------------
__global__ __launch_bounds__(256) void k_transpose(const float* __restrict__ x,
                                                   __half* __restrict__ xt) {
    const int h  = blockIdx.x;
    const int lc = blockIdx.y;             // chunk of 64 l-values
    __shared__ float raw[128][65];
    const float* xh = x + (size_t)h * D_ * L_ + (size_t)lc * 64;
    const int t = threadIdx.x;
    const int r0 = t >> 4;                 // 0..15
    const int c4 = (t & 15) << 2;          // 0,4,..,60
#pragma unroll
    for (int i = 0; i < 8; ++i) {
        const int d = i * 16 + r0;
        const float4 v = *(const float4*)(xh + (size_t)d * L_ + c4);
        raw[d][c4 + 0] = v.x; raw[d][c4 + 1] = v.y;
        raw[d][c4 + 2] = v.z; raw[d][c4 + 3] = v.w;
    }
    __syncthreads();
    const int lane = t & 63, w = t >> 6;
    __half2* xth = (__half2*)(xt + (size_t)h * L_ * D_ + (size_t)lc * 64 * D_);
#pragma unroll
    for (int i = 0; i < 16; ++i) {
        const int jl = w * 16 + i;
        const float a = raw[2 * lane][jl];
        const float b = raw[2 * lane + 1][jl];
        xth[(size_t)jl * 64 + lane] = __floats2half2_rn(a, b);
    }
}

// ---------------------------------------------------------------------------
// Kernel 2: symmetric panel-persistent Gram GEMM + exp epilogue.
//   Block = 512 thr (8 waves, 4 row-groups x 2 col-groups), 1 block/CU.
//   Block (h,pid) handles panels p=pid and p=7-pid (256 rows each),
//   stepping ct over 128-col tiles ct = 2p..15 (upper triangle), B dbuf.
//   Per wave sub-tile state vs its 128-row tile rtile=2p+(wr>>1):
//     ct<rtile: excluded (transpose computed elsewhere)
//     ct==rtile: diagonal (count once)
//     ct>rtile: off-diagonal (contributes both directions via symmetry)
//   PASS 1 slots (stride 9):  0..7 col-sum partials, 8 row sums
//   PASS 2 slots (stride 10): 0..7 direct partials, 8 row-weighted, 9 diag
// ---------------------------------------------------------------------------
template <int PASS>
__global__ __launch_bounds__(512, 2) void k_gemm(const __half* __restrict__ xt,
                                                 const float* __restrict__ ainv,
                                                 float* __restrict__ zw) {
    __shared__ char  smA[65536];           // 256 rows x 256B (swizzled)
    __shared__ char  smB[2][32768];        // 128 rows x 256B, double-buffered
    __shared__ float csum[2][4][128];
    __shared__ float zfin[2][256];

    const int bid = blockIdx.x;
    const int xq  = bid >> 3;
    const int pid = xq & 3;
    const int h   = ((xq >> 2) << 3) | (bid & 7);   // same-head blocks -> same XCD
    const int SLOTS = (PASS == 1) ? 9 : 10;

    const int t    = threadIdx.x;
    const int lane = t & 63;
    const int wid  = t >> 6;
    const int wr   = wid >> 1;             // 0..3: 64-row group
    const int wc   = wid & 1;              // 0..1: 64-col group
    const int lo   = lane & 15, hi = lane >> 4;
    const unsigned sx = (unsigned)((lane & 7) << 4);

    const char* xh = (const char*)(xt + (size_t)h * (L_ * D_));
    float* zwh = zw + (((size_t)h * SLOTS) << 11);

#pragma unroll 1
    for (int pp = 0; pp < 2; ++pp) {
        const int p     = pp ? (7 - pid) : pid;
        const int nst   = 16 - 2 * p;
        const int rtile = 2 * p + (wr >> 1);

        stage_tile<8>(xh + (size_t)(2 * p) * 32768, smA, wid, lane);
        stage_tile<4>(xh + (size_t)(2 * p) * 32768, smB[0], wid, lane);

        float rs[4][4] = {};               // pass1: row sums; pass2: row-weighted
        float ar[4][4];                    // pass2: ainv of this lane's panel rows
        if (PASS == 2) {
#pragma unroll
            for (int fm = 0; fm < 4; ++fm)
#pragma unroll
                for (int r = 0; r < 4; ++r)
                    ar[fm][r] = ainv[((size_t)h << 11) + p * 256 + wr * 64 + fm * 16 + hi * 4 + r];
        }
        __syncthreads();

#pragma unroll 1
        for (int it = 0; it < nst; ++it) {
            const int ct = 2 * p + it;
            if (it + 1 < nst)
                stage_tile<4>(xh + (size_t)(ct + 1) * 32768, smB[(it + 1) & 1], wid, lane);

            float acol[4];
            if (PASS == 2) {
#pragma unroll
                for (int fn = 0; fn < 4; ++fn)
                    acol[fn] = ainv[((size_t)h << 11) + ct * 128 + wc * 64 + fn * 16 + lo];
            }

            const int rel = ct - rtile;
            float cs[4] = {0.f, 0.f, 0.f, 0.f};
            if (rel >= 0) {
                f32x4 acc[4][4] = {};
                const char* tb = smB[it & 1];
#pragma unroll
                for (int s = 0; s < 4; ++s) {
                    half8 a[4], b[4];
                    const unsigned inr = ((unsigned)(s * 64 + hi * 16)) ^ sx;
#pragma unroll
                    for (int f = 0; f < 4; ++f) {
                        a[f] = *(const half8*)(smA + (unsigned)(wr * 64 + f * 16 + lo) * 256 + inr);
                        b[f] = *(const half8*)(tb  + (unsigned)(wc * 64 + f * 16 + lo) * 256 + inr);
                    }
#pragma unroll
                    for (int fm = 0; fm < 4; ++fm)
#pragma unroll
                        for (int fn = 0; fn < 4; ++fn)
                            acc[fm][fn] = __builtin_amdgcn_mfma_f32_16x16x32_f16(
                                a[fm], b[fn], acc[fm][fn], 0, 0, 0);
                }
#pragma unroll
                for (int fm = 0; fm < 4; ++fm)
#pragma unroll
                    for (int fn = 0; fn < 4; ++fn)
#pragma unroll
                        for (int r = 0; r < 4; ++r) {
                            const float e = __expf(acc[fm][fn][r] * RSCALE);
                            if (PASS == 1) {
                                rs[fm][r] += e;
                                if (rel > 0) cs[fn] += e;
                            } else {
                                cs[fn] += ar[fm][r] * e;            // direct (diag+off)
                                if (rel > 0) rs[fm][r] += acol[fn] * e;  // row-weighted
                            }
                        }
            }
#pragma unroll
            for (int fn = 0; fn < 4; ++fn) {
                cs[fn] += __shfl_xor(cs[fn], 16, 64);
                cs[fn] += __shfl_xor(cs[fn], 32, 64);
            }
            if (lane < 16) {
#pragma unroll
                for (int fn = 0; fn < 4; ++fn)
                    csum[it & 1][wr][wc * 64 + fn * 16 + lane] = cs[fn];
            }
            __syncthreads();
            if (t < 128) {
                const float su = csum[it & 1][0][t] + csum[it & 1][1][t];
                const float sl = csum[it & 1][2][t] + csum[it & 1][3][t];
                const size_t o = (size_t)ct * 128 + t;
                if (PASS == 1) {
                    zwh[((size_t)p << 11) + o] = su + sl;   // it==0 writes unread 0s
                } else {
                    if (it == 0)      zwh[((size_t)9 << 11) + o] = su + sl;  // diag (sl=0)
                    else if (it == 1) { zwh[((size_t)p << 11) + o] = su;     // upper off-diag
                                        zwh[((size_t)9 << 11) + o] = sl; }   // lower diag
                    else              zwh[((size_t)p << 11) + o] = su + sl;
                }
            }
        }

        // panel-end: reduce rs over the 16 col-lanes, combine across wc
#pragma unroll
        for (int fm = 0; fm < 4; ++fm)
#pragma unroll
            for (int r = 0; r < 4; ++r) {
                float v = rs[fm][r];
                v += __shfl_xor(v, 1, 64);
                v += __shfl_xor(v, 2, 64);
                v += __shfl_xor(v, 4, 64);
                v += __shfl_xor(v, 8, 64);
                if (lo == 0) zfin[wc][wr * 64 + fm * 16 + hi * 4 + r] = v;
            }
        __syncthreads();
        if (t < 256)
            zwh[((size_t)8 << 11) + p * 256 + t] = zfin[0][t] + zfin[1][t];
        __syncthreads();
    }
}

// ---------------------------------------------------------------------------
// Kernel 3: Z[h][l] = slot8 + sum_{2p<q} slot_p ; Ainv = 1/Z   (q = l>>7)
// ---------------------------------------------------------------------------
__global__ __launch_bounds__(256) void k_reduceZ(const float* __restrict__ zp,
                                                 float* __restrict__ ainv) {
    const int i = blockIdx.x * 256 + threadIdx.x;   // over H_*L_
    const int h = i >> 11, l = i & 2047, q = l >> 7;
    float z = zp[(((size_t)h * 9 + 8) << 11) + l];
#pragma unroll
    for (int p = 0; p < 8; ++p)
        if (2 * p < q) z += zp[(((size_t)h * 9 + p) << 11) + l];
    ainv[i] = 1.0f / z;
}

// ---------------------------------------------------------------------------
// Kernel 4: w[m] = slot8+slot9+sum_{2p<q} slot_p ; out = (1/L) x . w
// ---------------------------------------------------------------------------
__global__ __launch_bounds__(256) void k_out(const float* __restrict__ x,
                                             const float* __restrict__ wp,
                                             float* __restrict__ out) {
    __shared__ float wl[L_];
    const int h = blockIdx.x >> 2, qb = blockIdx.x & 3;
    const int t = threadIdx.x, lane = t & 63, wid = t >> 6;
    for (int c = t; c < L_; c += 256) {
        const int q = c >> 7;
        float s = wp[(((size_t)h * 10 + 8) << 11) + c]
                + wp[(((size_t)h * 10 + 9) << 11) + c];
#pragma unroll
        for (int p = 0; p < 8; ++p)
            if (2 * p < q) s += wp[(((size_t)h * 10 + p) << 11) + c];
        wl[c] = s;
    }
    __syncthreads();
#pragma unroll 1
    for (int it = 0; it < 8; ++it) {
        const int d = qb * 32 + wid * 8 + it;
        const float* xr = x + ((size_t)h * D_ + d) * L_;
        float s = 0.0f;
#pragma unroll
        for (int kk = 0; kk < 8; ++kk) {
            const int m = kk * 256 + lane * 4;
            const float4 xv = *(const float4*)(xr + m);
            const float4 wv = *(const float4*)(wl + m);
            s += xv.x * wv.x + xv.y * wv.y + xv.z * wv.z + xv.w * wv.w;
        }
#pragma unroll
        for (int dm = 1; dm < 64; dm <<= 1) s += __shfl_xor(s, dm, 64);
        if (lane == 0) out[(size_t)h * D_ + d] = s * (1.0f / (float)L_);
    }
}

// ---------------------------------------------------------------------------
extern "C" void kernel_launch(void* const* d_in, const int* in_sizes, int n_in,
                              void* d_out, int out_size, void* d_ws, size_t ws_size,
                              hipStream_t stream) {
    const float* x = (const float*)d_in[0];
    float* out = (float*)d_out;
    char* ws = (char*)d_ws;

    // workspace: xt 33,554,432 | zp/wp alias (max 10 slots) 5,242,880 | ainv 524,288
    __half* xt  = (__half*)(ws);
    float* zwp  = (float*)(ws + 33554432);
    float* ainv = (float*)(ws + 33554432 + 5242880);

    k_transpose<<<dim3(H_, L_ / 64), 256, 0, stream>>>(x, xt);
    k_gemm<1><<<256, 512, 0, stream>>>(xt, ainv, zwp);
    k_reduceZ<<<(H_ * L_) / 256, 256, 0, stream>>>(zwp, ainv);
    k_gemm<2><<<256, 512, 0, stream>>>(xt, ainv, zwp);
    k_out<<<H_ * 4, 256, 0, stream>>>(x, zwp, out);
}

// Round 3
// 158.004 us; speedup vs baseline: 1.7790x; 1.0769x over previous
//
#include <hip/hip_runtime.h>
#include <hip/hip_fp16.h>

#define H_  64      // B*N heads
#define D_  128
#define L_  2048
#define PRE 0.35709578f   // sqrt(log2(e)/sqrt(128)) folded into xt; exp(S/sqrt(D)) = 2^(S')

typedef _Float16 half8 __attribute__((ext_vector_type(8)));
typedef float    f32x4 __attribute__((ext_vector_type(4)));

__device__ __forceinline__ float fast_exp2(float x) {
#if __has_builtin(__builtin_amdgcn_exp2f)
    return __builtin_amdgcn_exp2f(x);
#else
    return __builtin_exp2f(x);
#endif
}

__device__ __forceinline__ void gload16(const void* g, void* l) {
    __builtin_amdgcn_global_load_lds(
        (const __attribute__((address_space(1))) void*)g,
        (__attribute__((address_space(3))) void*)l,
        16, 0, 0);
}

// Stage a 32KB tile (128 rows x 256B) with 256 threads: linear LDS dest,
// pre-swizzled global source. Swizzle: byte ^= (row&7)<<4 within each row.
__device__ __forceinline__ void stage32k(const char* __restrict__ src,
                                         char* __restrict__ dst,
                                         int wid, int lane) {
#pragma unroll
    for (int j = 0; j < 8; ++j) {
        const unsigned o   = (unsigned)(wid * 8 + j) * 1024u + (unsigned)lane * 16u;
        const unsigned row = o >> 8;
        const unsigned so  = (o & ~255u) | ((o & 255u) ^ ((row & 7u) << 4));
        gload16(src + so, dst + (size_t)(wid * 8 + j) * 1024u);
    }
}

// ---------------------------------------------------------------------------
// Kernel 1: x [H][D][L] fp32 -> xt [H][L][D] fp16, scaled by PRE
// ---------------------------------------------------------------------------
__global__ __launch_bounds__(256) void k_transpose(const float* __restrict__ x,
                                                   __half* __restrict__ xt) {
    const int h  = blockIdx.x;
    const int lc = blockIdx.y;             // chunk of 64 l-values
    __shared__ float raw[128][65];
    const float* xh = x + (size_t)h * D_ * L_ + (size_t)lc * 64;
    const int t = threadIdx.x;
    const int r0 = t >> 4;                 // 0..15
    const int c4 = (t & 15) << 2;          // 0,4,..,60
#pragma unroll
    for (int i = 0; i < 8; ++i) {
        const int d = i * 16 + r0;
        const float4 v = *(const float4*)(xh + (size_t)d * L_ + c4);
        raw[d][c4 + 0] = v.x; raw[d][c4 + 1] = v.y;
        raw[d][c4 + 2] = v.z; raw[d][c4 + 3] = v.w;
    }
    __syncthreads();
    const int lane = t & 63, w = t >> 6;
    __half2* xth = (__half2*)(xt + (size_t)h * L_ * D_ + (size_t)lc * 64 * D_);
#pragma unroll
    for (int i = 0; i < 16; ++i) {
        const int jl = w * 16 + i;
        const float a = raw[2 * lane][jl] * PRE;
        const float b = raw[2 * lane + 1][jl] * PRE;
        xth[(size_t)jl * 64 + lane] = __floats2half2_rn(a, b);
    }
}

// ---------------------------------------------------------------------------
// Kernel 2: symmetric panel-persistent Gram GEMM + exp2 epilogue.
//   256 thr (4 waves 2x2), tile 128x128, LDS ~66KB -> 2 blocks/CU (desynced).
//   Block (h,pid) does panels p=pid and p=15-pid: 17 uniform steps total.
//   Step it: ct = p+it.  it==0 = diagonal (B read from smA, no stage).
//   Slots (stride 17): 0..14 off-diag col partials (from panel p, p<ct),
//                      15 row-accumulated, 16 diag direct (pass2 only).
// ---------------------------------------------------------------------------
template <int PASS>
__global__ __launch_bounds__(256, 2) void k_gemm(const __half* __restrict__ xt,
                                                 const float* __restrict__ ainv,
                                                 float* __restrict__ zw) {
    __shared__ char  smA[32768];
    __shared__ char  smB[32768];
    __shared__ float csum[2][128];
    __shared__ float zfin[2][128];

    const int bid = blockIdx.x;
    const int res = bid & 7;               // XCD id; head group pinned per XCD
    const int j   = bid >> 3;
    const int h   = ((j >> 3) << 3) | res;
    const int pid = j & 7;

    const int t    = threadIdx.x;
    const int lane = t & 63;
    const int wid  = t >> 6;
    const int wr   = wid >> 1, wc = wid & 1;
    const int lo   = lane & 15, hi = lane >> 4;
    const unsigned sx = (unsigned)((lane & 7) << 4);

    const char*  xh  = (const char*)(xt + (size_t)h * (L_ * D_));
    float*       zwh = zw + ((size_t)h * 17 << 11);
    const float* ah  = ainv + ((size_t)h << 11);

#pragma unroll 1
    for (int pp = 0; pp < 2; ++pp) {
        const int p   = pp ? (15 - pid) : pid;
        const int nst = 16 - p;

        stage32k(xh + (size_t)p * 32768, smA, wid, lane);

        float rs[4][4] = {};               // pass1: row sums; pass2: sym row-weighted
        float ar[4][4];
        if (PASS == 2) {
#pragma unroll
            for (int fm = 0; fm < 4; ++fm)
#pragma unroll
                for (int r = 0; r < 4; ++r)
                    ar[fm][r] = ah[p * 128 + wr * 64 + fm * 16 + hi * 4 + r];
        }
        __syncthreads();                   // smA ready (also: prev panel reads done)

#pragma unroll 1
        for (int it = 0; it < nst; ++it) {
            const int ct = p + it;
            const char* tb;
            if (it == 0) {
                tb = smA;
            } else {
                stage32k(xh + (size_t)ct * 32768, smB, wid, lane);
                __syncthreads();           // smB ready (prev reads done via csum barrier)
                tb = smB;
            }
            float acol[4];
            if (PASS == 2) {
#pragma unroll
                for (int fn = 0; fn < 4; ++fn)
                    acol[fn] = ah[ct * 128 + wc * 64 + fn * 16 + lo];
            }

            f32x4 acc[4][4] = {};
            __builtin_amdgcn_s_setprio(1);
#pragma unroll
            for (int s = 0; s < 4; ++s) {
                half8 a[4], b[4];
                const unsigned inr = ((unsigned)(s * 64 + hi * 16)) ^ sx;
#pragma unroll
                for (int f = 0; f < 4; ++f) {
                    a[f] = *(const half8*)(smA + (unsigned)(wr * 64 + f * 16 + lo) * 256 + inr);
                    b[f] = *(const half8*)(tb  + (unsigned)(wc * 64 + f * 16 + lo) * 256 + inr);
                }
#pragma unroll
                for (int fm = 0; fm < 4; ++fm)
#pragma unroll
                    for (int fn = 0; fn < 4; ++fn)
                        acc[fm][fn] = __builtin_amdgcn_mfma_f32_16x16x32_f16(
                            a[fm], b[fn], acc[fm][fn], 0, 0, 0);
            }
            __builtin_amdgcn_s_setprio(0);

            if (PASS == 1 && it == 0) {
                // diagonal: rows only (cs would double-count); no write, no barrier
#pragma unroll
                for (int fm = 0; fm < 4; ++fm)
#pragma unroll
                    for (int fn = 0; fn < 4; ++fn)
#pragma unroll
                        for (int r = 0; r < 4; ++r)
                            rs[fm][r] += fast_exp2(acc[fm][fn][r]);
            } else {
                float cs[4] = {0.f, 0.f, 0.f, 0.f};
#pragma unroll
                for (int fm = 0; fm < 4; ++fm)
#pragma unroll
                    for (int fn = 0; fn < 4; ++fn)
#pragma unroll
                        for (int r = 0; r < 4; ++r) {
                            const float e = fast_exp2(acc[fm][fn][r]);
                            if (PASS == 1) {
                                rs[fm][r] += e;
                                cs[fn]    += e;
                            } else {
                                cs[fn] += ar[fm][r] * e;                  // direct
                                if (it > 0) rs[fm][r] += acol[fn] * e;    // symmetric
                            }
                        }
#pragma unroll
                for (int fn = 0; fn < 4; ++fn) {
                    cs[fn] += __shfl_xor(cs[fn], 16, 64);
                    cs[fn] += __shfl_xor(cs[fn], 32, 64);
                }
                if (lane < 16) {
#pragma unroll
                    for (int fn = 0; fn < 4; ++fn)
                        csum[wr][wc * 64 + fn * 16 + lane] = cs[fn];
                }
                __syncthreads();
                if (t < 128) {
                    const float s2 = csum[0][t] + csum[1][t];
                    const size_t o = ((size_t)ct << 7) + t;
                    if (PASS == 2 && it == 0) zwh[((size_t)16 << 11) + o] = s2;
                    else                      zwh[((size_t)p  << 11) + o] = s2;
                }
            }
        }

        // panel end: reduce rs over the 16 col-lanes, combine across wc
#pragma unroll
        for (int fm = 0; fm < 4; ++fm)
#pragma unroll
            for (int r = 0; r < 4; ++r) {
                float v = rs[fm][r];
                v += __shfl_xor(v, 1, 64);
                v += __shfl_xor(v, 2, 64);
                v += __shfl_xor(v, 4, 64);
                v += __shfl_xor(v, 8, 64);
                if (lo == 0) zfin[wc][wr * 64 + fm * 16 + hi * 4 + r] = v;
            }
        __syncthreads();
        if (t < 128)
            zwh[((size_t)15 << 11) + ((size_t)p << 7) + t] = zfin[0][t] + zfin[1][t];
        __syncthreads();                   // zfin read done before next panel reuses it
    }
}

// ---------------------------------------------------------------------------
// Kernel 3: Z[l] = slot15 + sum_{p<q} slot_p ; Ainv = 1/Z   (q = l>>7)
// ---------------------------------------------------------------------------
__global__ __launch_bounds__(256) void k_reduceZ(const float* __restrict__ zp,
                                                 float* __restrict__ ainv) {
    const int i = blockIdx.x * 256 + threadIdx.x;   // over H_*L_
    const int h = i >> 11, l = i & 2047, q = l >> 7;
    float z = zp[(((size_t)h * 17 + 15) << 11) + l];
#pragma unroll
    for (int p = 0; p < 15; ++p)
        if (p < q) z += zp[(((size_t)h * 17 + p) << 11) + l];
    ainv[i] = 1.0f / z;
}

// ---------------------------------------------------------------------------
// Kernel 4: w[m] = slot15 + slot16 + sum_{p<q} slot_p ; out = (1/L) x . w
// ---------------------------------------------------------------------------
__global__ __launch_bounds__(256) void k_out(const float* __restrict__ x,
                                             const float* __restrict__ wp,
                                             float* __restrict__ out) {
    __shared__ float wl[L_];
    const int h = blockIdx.x >> 2, qb = blockIdx.x & 3;
    const int t = threadIdx.x, lane = t & 63, wid = t >> 6;
    for (int c = t; c < L_; c += 256) {
        const int q = c >> 7;
        float s = wp[(((size_t)h * 17 + 15) << 11) + c]
                + wp[(((size_t)h * 17 + 16) << 11) + c];
#pragma unroll
        for (int p = 0; p < 15; ++p)
            if (p < q) s += wp[(((size_t)h * 17 + p) << 11) + c];
        wl[c] = s;
    }
    __syncthreads();
#pragma unroll 1
    for (int it = 0; it < 8; ++it) {
        const int d = qb * 32 + wid * 8 + it;
        const float* xr = x + ((size_t)h * D_ + d) * L_;
        float s = 0.0f;
#pragma unroll
        for (int kk = 0; kk < 8; ++kk) {
            const int m = kk * 256 + lane * 4;
            const float4 xv = *(const float4*)(xr + m);
            const float4 wv = *(const float4*)(wl + m);
            s += xv.x * wv.x + xv.y * wv.y + xv.z * wv.z + xv.w * wv.w;
        }
#pragma unroll
        for (int dm = 1; dm < 64; dm <<= 1) s += __shfl_xor(s, dm, 64);
        if (lane == 0) out[(size_t)h * D_ + d] = s * (1.0f / (float)L_);
    }
}

// ---------------------------------------------------------------------------
extern "C" void kernel_launch(void* const* d_in, const int* in_sizes, int n_in,
                              void* d_out, int out_size, void* d_ws, size_t ws_size,
                              hipStream_t stream) {
    const float* x = (const float*)d_in[0];
    float* out = (float*)d_out;
    char* ws = (char*)d_ws;

    // workspace: xt 33,554,432 | zwp 17 slots = 8,912,896 | ainv 524,288
    __half* xt  = (__half*)(ws);
    float* zwp  = (float*)(ws + 33554432);
    float* ainv = (float*)(ws + 33554432 + 8912896);

    k_transpose<<<dim3(H_, L_ / 64), 256, 0, stream>>>(x, xt);
    k_gemm<1><<<512, 256, 0, stream>>>(xt, ainv, zwp);
    k_reduceZ<<<(H_ * L_) / 256, 256, 0, stream>>>(zwp, ainv);
    k_gemm<2><<<512, 256, 0, stream>>>(xt, ainv, zwp);
    k_out<<<H_ * 4, 256, 0, stream>>>(x, zwp, out);
}